// Round 3
// baseline (239.128 us; speedup 1.0000x reference)
//
#include <hip/hip_runtime.h>
#include <hip/hip_bf16.h>
#include <stdint.h>

// ---------------------------------------------------------------------------
// OptimizedMultiHeadAttn: x:[2,2048,1024] f32, attn_w:[3072,1024], attn_b:[3072],
// proj_w:[1024,1024], proj_b:[1024]  ->  out:[2,2048,1024] f32
// Pipeline: cvt3(x,attn_w,proj_w -> bf16) -> QKV gemm_bt (scatter to Q/K/V^T)
//           -> flash attention (causal, 8-wave K-split) -> proj gemm_bt
// ---------------------------------------------------------------------------

typedef __bf16 bf16_t;
typedef __bf16 bf16x8 __attribute__((ext_vector_type(8)));
typedef float f32x4 __attribute__((ext_vector_type(4)));

#define B_SZ 2
#define S_LEN 2048
#define D_MODEL 1024
#define N_HEADS 16
#define D_HEAD 64
#define M_ROWS (B_SZ * S_LEN)          // 4096
#define QKV_N (3 * N_HEADS * D_HEAD)   // 3072

// Q pre-scale: 1/sqrt(64) * log2(e)  (softmax runs in exp2 domain)
#define Q_SCALE 0.1803368801111204f

// workspace layout (bytes); total 48 MiB
#define OFF_XB  (0ull)          // x bf16      [4096,1024]  8 MiB
#define OFF_WB  (8ull  << 20)   // attn_w bf16 [3072,1024]  6 MiB
#define OFF_PWB (14ull << 20)   // proj_w bf16 [1024,1024]  2 MiB
#define OFF_Q   (16ull << 20)   // Q bf16 [B,H,S,DK], pre-scaled by Q_SCALE
#define OFF_K   (24ull << 20)   // K bf16 [B,H,S,DK]
#define OFF_VT  (32ull << 20)   // V^T bf16 [B,H,DK,S]
#define OFF_AO  (40ull << 20)   // attn out bf16 [4096,1024]

__device__ __forceinline__ unsigned short f2bf_u(float f) {
  union { float f; unsigned u; } v; v.f = f;
  unsigned r = v.u + 0x7fffu + ((v.u >> 16) & 1u);  // RNE
  return (unsigned short)(r >> 16);
}
__device__ __forceinline__ bf16_t f2bf(float f) {
  unsigned short u = f2bf_u(f);
  return __builtin_bit_cast(bf16_t, u);
}

// ---------------------------------------------------------------------------
// fused convert: x (n4a float4s) -> xb, attn_w (n4b) -> wb, proj_w (n4c) -> pwb
__global__ void cvt3_f32_bf16(const float* __restrict__ sa, bf16_t* __restrict__ da, int n4a,
                              const float* __restrict__ sb, bf16_t* __restrict__ db, int n4b,
                              const float* __restrict__ sc, bf16_t* __restrict__ dc, int n4c) {
  int i = blockIdx.x * blockDim.x + threadIdx.x;
  const float* s; bf16_t* d; int j = i;
  if (i < n4a) { s = sa; d = da; }
  else if ((j = i - n4a) < n4b) { s = sb; d = db; }
  else if ((j = i - n4a - n4b) < n4c) { s = sc; d = dc; }
  else return;
  float4 f = reinterpret_cast<const float4*>(s)[j];
  ushort4 o;
  o.x = f2bf_u(f.x); o.y = f2bf_u(f.y); o.z = f2bf_u(f.z); o.w = f2bf_u(f.w);
  reinterpret_cast<ushort4*>(d)[j] = o;
}

// ---------------------------------------------------------------------------
// gemm_bt: C[M,N] = A[M,K] * Bt[N,K]^T + bias, 128x128 tile, BK=64, 4 waves.
#define BM 128
#define BN 128
#define BK 64

__device__ __forceinline__ void gload_lds16(const bf16_t* g, bf16_t* l) {
  __builtin_amdgcn_global_load_lds((__attribute__((address_space(1))) void*)g,
                                   (__attribute__((address_space(3))) void*)l,
                                   16, 0, 0);
}

__device__ __forceinline__ bf16x8 lds_frag(const bf16_t* lds, int row, int kchunk) {
  int pos = kchunk ^ (row & 7);
  return *reinterpret_cast<const bf16x8*>(lds + row * BK + pos * 8);
}

// EPI 0: QKV epilogue (scatter bf16 Q/K/V^T, Q pre-scaled Q_SCALE)
// EPI 1: proj epilogue (f32 out + bias)
template <int EPI>
__global__ __launch_bounds__(256, 2) void gemm_bt(
    const bf16_t* __restrict__ A, const bf16_t* __restrict__ Bt,
    const float* __restrict__ bias,
    float* __restrict__ fout,
    bf16_t* __restrict__ qout, bf16_t* __restrict__ kout,
    bf16_t* __restrict__ vtout,
    int M, int N, int K) {
  __shared__ bf16_t As[BM * BK];
  __shared__ bf16_t Bs[BN * BK];
  const int tid = threadIdx.x;
  const int lane = tid & 63;
  const int wid = tid >> 6;
  const int wr = wid >> 1, wc = wid & 1;
  const int cl = lane & 15, hl = lane >> 4;
  const int m0 = blockIdx.y * BM, n0 = blockIdx.x * BN;

  f32x4 acc[4][4];
  #pragma unroll
  for (int m = 0; m < 4; ++m)
    #pragma unroll
    for (int n = 0; n < 4; ++n)
      acc[m][n] = (f32x4){0.f, 0.f, 0.f, 0.f};

  for (int kt = 0; kt < K; kt += BK) {
    #pragma unroll
    for (int it = 0; it < 4; ++it) {
      int chunk = it * 256 + tid;
      int row = chunk >> 3, cpos = chunk & 7;
      int csrc = cpos ^ (row & 7);                     // inverse-swizzled source
      bf16_t* ldsA = As + (it * 256 + wid * 64) * 8;   // wave-uniform dest base
      bf16_t* ldsB = Bs + (it * 256 + wid * 64) * 8;
      gload_lds16(A  + (size_t)(m0 + row) * K + kt + csrc * 8, ldsA);
      gload_lds16(Bt + (size_t)(n0 + row) * K + kt + csrc * 8, ldsB);
    }
    __syncthreads();

    bf16x8 af[2][4], bfr[2][4];
    #pragma unroll
    for (int kk = 0; kk < 2; ++kk) {
      #pragma unroll
      for (int m = 0; m < 4; ++m)
        af[kk][m] = lds_frag(As, wr * 64 + m * 16 + cl, kk * 4 + hl);
      #pragma unroll
      for (int n = 0; n < 4; ++n)
        bfr[kk][n] = lds_frag(Bs, wc * 64 + n * 16 + cl, kk * 4 + hl);
    }
    __builtin_amdgcn_s_setprio(1);
    #pragma unroll
    for (int m = 0; m < 4; ++m)
      #pragma unroll
      for (int n = 0; n < 4; ++n) {
        acc[m][n] = __builtin_amdgcn_mfma_f32_16x16x32_bf16(af[0][m], bfr[0][n], acc[m][n], 0, 0, 0);
        acc[m][n] = __builtin_amdgcn_mfma_f32_16x16x32_bf16(af[1][m], bfr[1][n], acc[m][n], 0, 0, 0);
      }
    __builtin_amdgcn_s_setprio(0);
    __syncthreads();
  }

  // epilogue: C/D layout col=lane&15, row=(lane>>4)*4+j (m89-verified)
  #pragma unroll
  for (int n = 0; n < 4; ++n) {
    int ng = n0 + wc * 64 + n * 16 + cl;
    float bv = bias[ng];
    if constexpr (EPI == 0) {
      int part = ng >> 10;         // 0=Q 1=K 2=V
      int r = ng & 1023;
      int h = r >> 6, dk = r & 63;
      #pragma unroll
      for (int m = 0; m < 4; ++m)
        #pragma unroll
        for (int j = 0; j < 4; ++j) {
          int mg = m0 + wr * 64 + m * 16 + hl * 4 + j;
          int b = mg >> 11, s = mg & 2047;
          float val = acc[m][n][j] + bv;
          size_t bh = (size_t)(b * N_HEADS + h);
          if (part == 0)
            qout[(bh * S_LEN + s) * D_HEAD + dk] = f2bf(val * Q_SCALE);
          else if (part == 1)
            kout[(bh * S_LEN + s) * D_HEAD + dk] = f2bf(val);
          else
            vtout[(bh * D_HEAD + dk) * S_LEN + s] = f2bf(val);
        }
    } else {
      #pragma unroll
      for (int m = 0; m < 4; ++m)
        #pragma unroll
        for (int j = 0; j < 4; ++j) {
          int mg = m0 + wr * 64 + m * 16 + hl * 4 + j;
          fout[(size_t)mg * N + ng] = acc[m][n][j] + bv;
        }
    }
  }
}

// ---------------------------------------------------------------------------
// Flash attention, causal, exp2-domain softmax. Grid (B*H, S/128).
// Block = 8 waves (512 thr) covering 128 q-rows with a 2-way K-split:
//   waves 0-3: kt in [0, qt+1)           (row-groups wq=w&3)
//   waves 4-7: kt in [qt+1, 2qt+2)       (same rows, upper K half)
// Both halves do exactly qt+1 iterations (balanced). Partials merged via LDS.
// Each wave owns rows {qbase+wq*16, qbase+64+wq*16} (two 16-row fragments).
__global__ __launch_bounds__(512, 4) void attn_fwd(
    const bf16_t* __restrict__ q,    // [B,H,S,DK], pre-scaled by Q_SCALE
    const bf16_t* __restrict__ k,    // [B,H,S,DK]
    const bf16_t* __restrict__ vt,   // [B,H,DK,S]
    bf16_t* __restrict__ ao) {       // [B*S, H*DK]
  const int bh = blockIdx.x;
  const int qt = (S_LEN / 128 - 1) - blockIdx.y;   // long blocks first
  const int tid = threadIdx.x;
  const int lane = tid & 63, w = tid >> 6;
  const int wq = w & 3, half = w >> 2;
  const int cl = lane & 15, hl = lane >> 4;
  const bf16_t* qb = q + (size_t)bh * S_LEN * D_HEAD;
  const bf16_t* kb = k + (size_t)bh * S_LEN * D_HEAD;
  const bf16_t* vb = vt + (size_t)bh * D_HEAD * S_LEN;
  const int qbase = qt * 128;
  const int row0[2] = { qbase + wq * 16, qbase + 64 + wq * 16 };

  // smem: phase 1 = per-wave P tiles [8][32][72] bf16 (36864 B)
  //       phase 2 = merge buffer [4][64][48] f32 (49152 B)  (barrier-separated)
  __shared__ __align__(16) char smem[49152];
  auto plds = reinterpret_cast<bf16_t(*)[32][72]>(smem);
  float* mbuf = reinterpret_cast<float*>(smem);

  // Q fragments (A-operand): row=lane&15, k=(lane>>4)*8 (+32 for second half)
  bf16x8 qf[2][2];
  #pragma unroll
  for (int rf = 0; rf < 2; ++rf) {
    const bf16_t* qr = qb + (size_t)(row0[rf] + cl) * D_HEAD + hl * 8;
    qf[rf][0] = *reinterpret_cast<const bf16x8*>(qr);
    qf[rf][1] = *reinterpret_cast<const bf16x8*>(qr + 32);
  }

  float mrow[2][4], lrow[2][4];
  f32x4 acco[2][4];
  #pragma unroll
  for (int rf = 0; rf < 2; ++rf) {
    #pragma unroll
    for (int j = 0; j < 4; ++j) { mrow[rf][j] = -1e30f; lrow[rf][j] = 0.f; }
    #pragma unroll
    for (int db = 0; db < 4; ++db) acco[rf][db] = (f32x4){0.f, 0.f, 0.f, 0.f};
  }

  const int kt0 = half ? (qt + 1) : 0;
  const int kt1 = half ? (2 * qt + 2) : (qt + 1);
  for (int kt = kt0; kt < kt1; ++kt) {
    // K fragments, shared by both row-fragments
    bf16x8 kf[4][2];
    #pragma unroll
    for (int nb = 0; nb < 4; ++nb) {
      const bf16_t* kr = kb + (size_t)(kt * 64 + nb * 16 + cl) * D_HEAD + hl * 8;
      kf[nb][0] = *reinterpret_cast<const bf16x8*>(kr);
      kf[nb][1] = *reinterpret_cast<const bf16x8*>(kr + 32);
    }

    const bool act0 = (kt * 64) <= (row0[0] + 15);
    const bool act1 = (kt * 64) <= (row0[1] + 15);

    // QK^T for both fragments
    f32x4 sacc[2][4];
    __builtin_amdgcn_s_setprio(1);
    #pragma unroll
    for (int rf = 0; rf < 2; ++rf) {
      const bool act = rf ? act1 : act0;
      if (!act) continue;
      #pragma unroll
      for (int nb = 0; nb < 4; ++nb) {
        f32x4 s = (f32x4){0.f, 0.f, 0.f, 0.f};
        s = __builtin_amdgcn_mfma_f32_16x16x32_bf16(qf[rf][0], kf[nb][0], s, 0, 0, 0);
        s = __builtin_amdgcn_mfma_f32_16x16x32_bf16(qf[rf][1], kf[nb][1], s, 0, 0, 0);
        sacc[rf][nb] = s;
      }
    }
    __builtin_amdgcn_s_setprio(0);

    // V fragments issued early (in flight under softmax)
    bf16x8 vf[4][2];
    #pragma unroll
    for (int db = 0; db < 4; ++db) {
      const bf16_t* vr = vb + (size_t)(db * 16 + cl) * S_LEN + kt * 64 + hl * 8;
      vf[db][0] = *reinterpret_cast<const bf16x8*>(vr);
      vf[db][1] = *reinterpret_cast<const bf16x8*>(vr + 32);
    }

    // softmax (exp2 domain) + P->LDS
    #pragma unroll
    for (int rf = 0; rf < 2; ++rf) {
      const bool act = rf ? act1 : act0;
      if (!act) continue;
      if (kt * 64 + 63 > row0[rf]) {  // diagonal overlap: causal mask
        #pragma unroll
        for (int nb = 0; nb < 4; ++nb)
          #pragma unroll
          for (int j = 0; j < 4; ++j) {
            int colg = kt * 64 + nb * 16 + cl;
            int rowg = row0[rf] + hl * 4 + j;
            if (colg > rowg) sacc[rf][nb][j] = -1e30f;
          }
      }
      #pragma unroll
      for (int j = 0; j < 4; ++j) {
        float tmax = fmaxf(fmaxf(sacc[rf][0][j], sacc[rf][1][j]),
                           fmaxf(sacc[rf][2][j], sacc[rf][3][j]));
        tmax = fmaxf(tmax, __shfl_xor(tmax, 1));
        tmax = fmaxf(tmax, __shfl_xor(tmax, 2));
        tmax = fmaxf(tmax, __shfl_xor(tmax, 4));
        tmax = fmaxf(tmax, __shfl_xor(tmax, 8));
        float mnew = fmaxf(mrow[rf][j], tmax);
        float corr = __builtin_amdgcn_exp2f(mrow[rf][j] - mnew);
        mrow[rf][j] = mnew;
        float rsum = 0.f;
        #pragma unroll
        for (int nb = 0; nb < 4; ++nb) {
          float p = __builtin_amdgcn_exp2f(sacc[rf][nb][j] - mnew);
          sacc[rf][nb][j] = p;
          rsum += p;
        }
        rsum += __shfl_xor(rsum, 1);
        rsum += __shfl_xor(rsum, 2);
        rsum += __shfl_xor(rsum, 4);
        rsum += __shfl_xor(rsum, 8);
        lrow[rf][j] = lrow[rf][j] * corr + rsum;
        #pragma unroll
        for (int db = 0; db < 4; ++db) acco[rf][db][j] *= corr;
      }
      #pragma unroll
      for (int nb = 0; nb < 4; ++nb)
        #pragma unroll
        for (int j = 0; j < 4; ++j)
          plds[w][rf * 16 + hl * 4 + j][nb * 16 + cl] = f2bf(sacc[rf][nb][j]);
    }

    // PV
    __builtin_amdgcn_s_setprio(1);
    #pragma unroll
    for (int rf = 0; rf < 2; ++rf) {
      const bool act = rf ? act1 : act0;
      if (!act) continue;
      bf16x8 pf0 = *reinterpret_cast<const bf16x8*>(&plds[w][rf * 16 + cl][hl * 8]);
      bf16x8 pf1 = *reinterpret_cast<const bf16x8*>(&plds[w][rf * 16 + cl][32 + hl * 8]);
      #pragma unroll
      for (int db = 0; db < 4; ++db) {
        acco[rf][db] = __builtin_amdgcn_mfma_f32_16x16x32_bf16(pf0, vf[db][0], acco[rf][db], 0, 0, 0);
        acco[rf][db] = __builtin_amdgcn_mfma_f32_16x16x32_bf16(pf1, vf[db][1], acco[rf][db], 0, 0, 0);
      }
    }
    __builtin_amdgcn_s_setprio(0);
  }

  // merge the two K-halves (waves w and w+4 hold partials for the same rows)
  __syncthreads();
  if (half) {
    float* p = mbuf + ((size_t)((w - 4) * 64 + lane)) * 48;
    #pragma unroll
    for (int rf = 0; rf < 2; ++rf) {
      #pragma unroll
      for (int db = 0; db < 4; ++db)
        #pragma unroll
        for (int j = 0; j < 4; ++j)
          p[rf * 16 + db * 4 + j] = acco[rf][db][j];
      #pragma unroll
      for (int j = 0; j < 4; ++j) {
        p[32 + rf * 4 + j] = mrow[rf][j];
        p[40 + rf * 4 + j] = lrow[rf][j];
      }
    }
  }
  __syncthreads();
  if (!half) {
    const float* p = mbuf + ((size_t)(w * 64 + lane)) * 48;
    const int b = bh >> 4, h = bh & 15;
    #pragma unroll
    for (int rf = 0; rf < 2; ++rf) {
      float c1[4], c2[4], linv[4];
      #pragma unroll
      for (int j = 0; j < 4; ++j) {
        float m2 = p[32 + rf * 4 + j];
        float l2 = p[40 + rf * 4 + j];
        float m = fmaxf(mrow[rf][j], m2);
        c1[j] = __builtin_amdgcn_exp2f(mrow[rf][j] - m);
        c2[j] = __builtin_amdgcn_exp2f(m2 - m);
        linv[j] = 1.f / (lrow[rf][j] * c1[j] + l2 * c2[j]);
      }
      #pragma unroll
      for (int db = 0; db < 4; ++db)
        #pragma unroll
        for (int j = 0; j < 4; ++j) {
          int rowg = row0[rf] + hl * 4 + j;
          float o = (acco[rf][db][j] * c1[j] + p[rf * 16 + db * 4 + j] * c2[j]) * linv[j];
          ao[((size_t)(b * S_LEN) + rowg) * D_MODEL + h * D_HEAD + db * 16 + cl] = f2bf(o);
        }
    }
  }
}

// ---------------------------------------------------------------------------
extern "C" void kernel_launch(void* const* d_in, const int* in_sizes, int n_in,
                              void* d_out, int out_size, void* d_ws, size_t ws_size,
                              hipStream_t stream) {
  const float* x      = (const float*)d_in[0];
  const float* attn_w = (const float*)d_in[1];
  const float* attn_b = (const float*)d_in[2];
  const float* proj_w = (const float*)d_in[3];
  const float* proj_b = (const float*)d_in[4];
  float* out = (float*)d_out;
  char* ws = (char*)d_ws;

  bf16_t* xb  = (bf16_t*)(ws + OFF_XB);
  bf16_t* wb  = (bf16_t*)(ws + OFF_WB);
  bf16_t* pwb = (bf16_t*)(ws + OFF_PWB);
  bf16_t* qb  = (bf16_t*)(ws + OFF_Q);
  bf16_t* kb  = (bf16_t*)(ws + OFF_K);
  bf16_t* vtb = (bf16_t*)(ws + OFF_VT);
  bf16_t* aob = (bf16_t*)(ws + OFF_AO);

  const int n4a = M_ROWS * D_MODEL / 4;
  const int n4b = QKV_N * D_MODEL / 4;
  const int n4c = D_MODEL * D_MODEL / 4;
  const int n4 = n4a + n4b + n4c;
  cvt3_f32_bf16<<<(n4 + 255) / 256, 256, 0, stream>>>(x, xb, n4a, attn_w, wb, n4b,
                                                      proj_w, pwb, n4c);

  gemm_bt<0><<<dim3(QKV_N / BN, M_ROWS / BM), 256, 0, stream>>>(
      xb, wb, attn_b, nullptr, qb, kb, vtb, M_ROWS, QKV_N, D_MODEL);

  attn_fwd<<<dim3(B_SZ * N_HEADS, S_LEN / 128), 512, 0, stream>>>(qb, kb, vtb, aob);

  gemm_bt<1><<<dim3(D_MODEL / BN, M_ROWS / BM), 256, 0, stream>>>(
      aob, pwb, proj_b, out, nullptr, nullptr, nullptr, M_ROWS, D_MODEL, D_MODEL);
}

// Round 7
// 146.042 us; speedup vs baseline: 1.6374x; 1.6374x over previous
//
#include <hip/hip_runtime.h>
#include <hip/hip_bf16.h>
#include <stdint.h>

// ---------------------------------------------------------------------------
// OptimizedMultiHeadAttn: x:[2,2048,1024] f32, attn_w:[3072,1024], attn_b:[3072],
// proj_w:[1024,1024], proj_b:[1024]  ->  out:[2,2048,1024] f32
// Pipeline: cvt3(x,attn_w,proj_w -> bf16) -> QKV gemm_bt (scatter to Q/K/V^T)
//           -> flash attention (causal, 8-wave K-split) -> proj gemm_bt
//
// NOTE (R2 post-mortem): __launch_bounds__ 2nd arg behaves as CUDA
// minBlocksPerMultiprocessor on hipcc: (512,4) capped VGPR at 64 (4 blk x 8
// waves / 4 SIMD = 8 waves/EU -> 512/8 = 64) and spilled 154 MB to scratch.
// (512,2) -> 4 waves/EU -> 128 VGPR cap, fits the ~100-VGPR kernel.
// (R4/R5/R6: resubmissions — bench infra (UnresponsiveContainer) failed
// three times on the same pod; no measurement signal since R2.)
// ---------------------------------------------------------------------------

typedef __bf16 bf16_t;
typedef __bf16 bf16x8 __attribute__((ext_vector_type(8)));
typedef float f32x4 __attribute__((ext_vector_type(4)));

#define B_SZ 2
#define S_LEN 2048
#define D_MODEL 1024
#define N_HEADS 16
#define D_HEAD 64
#define M_ROWS (B_SZ * S_LEN)          // 4096
#define QKV_N (3 * N_HEADS * D_HEAD)   // 3072

// Q pre-scale: 1/sqrt(64) * log2(e)  (softmax runs in exp2 domain)
#define Q_SCALE 0.1803368801111204f

// workspace layout (bytes); total 48 MiB
#define OFF_XB  (0ull)          // x bf16      [4096,1024]  8 MiB
#define OFF_WB  (8ull  << 20)   // attn_w bf16 [3072,1024]  6 MiB
#define OFF_PWB (14ull << 20)   // proj_w bf16 [1024,1024]  2 MiB
#define OFF_Q   (16ull << 20)   // Q bf16 [B,H,S,DK], pre-scaled by Q_SCALE
#define OFF_K   (24ull << 20)   // K bf16 [B,H,S,DK]
#define OFF_VT  (32ull << 20)   // V^T bf16 [B,H,DK,S]
#define OFF_AO  (40ull << 20)   // attn out bf16 [4096,1024]

__device__ __forceinline__ unsigned short f2bf_u(float f) {
  union { float f; unsigned u; } v; v.f = f;
  unsigned r = v.u + 0x7fffu + ((v.u >> 16) & 1u);  // RNE
  return (unsigned short)(r >> 16);
}
__device__ __forceinline__ bf16_t f2bf(float f) {
  unsigned short u = f2bf_u(f);
  return __builtin_bit_cast(bf16_t, u);
}

// ---------------------------------------------------------------------------
// fused convert: x (n4a float4s) -> xb, attn_w (n4b) -> wb, proj_w (n4c) -> pwb
__global__ void cvt3_f32_bf16(const float* __restrict__ sa, bf16_t* __restrict__ da, int n4a,
                              const float* __restrict__ sb, bf16_t* __restrict__ db, int n4b,
                              const float* __restrict__ sc, bf16_t* __restrict__ dc, int n4c) {
  int i = blockIdx.x * blockDim.x + threadIdx.x;
  const float* s; bf16_t* d; int j = i;
  if (i < n4a) { s = sa; d = da; }
  else if ((j = i - n4a) < n4b) { s = sb; d = db; }
  else if ((j = i - n4a - n4b) < n4c) { s = sc; d = dc; }
  else return;
  float4 f = reinterpret_cast<const float4*>(s)[j];
  ushort4 o;
  o.x = f2bf_u(f.x); o.y = f2bf_u(f.y); o.z = f2bf_u(f.z); o.w = f2bf_u(f.w);
  reinterpret_cast<ushort4*>(d)[j] = o;
}

// ---------------------------------------------------------------------------
// gemm_bt: C[M,N] = A[M,K] * Bt[N,K]^T + bias, 128x128 tile, BK=64, 4 waves.
#define BM 128
#define BN 128
#define BK 64

__device__ __forceinline__ void gload_lds16(const bf16_t* g, bf16_t* l) {
  __builtin_amdgcn_global_load_lds((__attribute__((address_space(1))) void*)g,
                                   (__attribute__((address_space(3))) void*)l,
                                   16, 0, 0);
}

__device__ __forceinline__ bf16x8 lds_frag(const bf16_t* lds, int row, int kchunk) {
  int pos = kchunk ^ (row & 7);
  return *reinterpret_cast<const bf16x8*>(lds + row * BK + pos * 8);
}

// EPI 0: QKV epilogue (scatter bf16 Q/K/V^T, Q pre-scaled Q_SCALE)
// EPI 1: proj epilogue (f32 out + bias)
template <int EPI>
__global__ __launch_bounds__(256, 2) void gemm_bt(
    const bf16_t* __restrict__ A, const bf16_t* __restrict__ Bt,
    const float* __restrict__ bias,
    float* __restrict__ fout,
    bf16_t* __restrict__ qout, bf16_t* __restrict__ kout,
    bf16_t* __restrict__ vtout,
    int M, int N, int K) {
  __shared__ bf16_t As[BM * BK];
  __shared__ bf16_t Bs[BN * BK];
  const int tid = threadIdx.x;
  const int lane = tid & 63;
  const int wid = tid >> 6;
  const int wr = wid >> 1, wc = wid & 1;
  const int cl = lane & 15, hl = lane >> 4;
  const int m0 = blockIdx.y * BM, n0 = blockIdx.x * BN;

  f32x4 acc[4][4];
  #pragma unroll
  for (int m = 0; m < 4; ++m)
    #pragma unroll
    for (int n = 0; n < 4; ++n)
      acc[m][n] = (f32x4){0.f, 0.f, 0.f, 0.f};

  for (int kt = 0; kt < K; kt += BK) {
    #pragma unroll
    for (int it = 0; it < 4; ++it) {
      int chunk = it * 256 + tid;
      int row = chunk >> 3, cpos = chunk & 7;
      int csrc = cpos ^ (row & 7);                     // inverse-swizzled source
      bf16_t* ldsA = As + (it * 256 + wid * 64) * 8;   // wave-uniform dest base
      bf16_t* ldsB = Bs + (it * 256 + wid * 64) * 8;
      gload_lds16(A  + (size_t)(m0 + row) * K + kt + csrc * 8, ldsA);
      gload_lds16(Bt + (size_t)(n0 + row) * K + kt + csrc * 8, ldsB);
    }
    __syncthreads();

    bf16x8 af[2][4], bfr[2][4];
    #pragma unroll
    for (int kk = 0; kk < 2; ++kk) {
      #pragma unroll
      for (int m = 0; m < 4; ++m)
        af[kk][m] = lds_frag(As, wr * 64 + m * 16 + cl, kk * 4 + hl);
      #pragma unroll
      for (int n = 0; n < 4; ++n)
        bfr[kk][n] = lds_frag(Bs, wc * 64 + n * 16 + cl, kk * 4 + hl);
    }
    __builtin_amdgcn_s_setprio(1);
    #pragma unroll
    for (int m = 0; m < 4; ++m)
      #pragma unroll
      for (int n = 0; n < 4; ++n) {
        acc[m][n] = __builtin_amdgcn_mfma_f32_16x16x32_bf16(af[0][m], bfr[0][n], acc[m][n], 0, 0, 0);
        acc[m][n] = __builtin_amdgcn_mfma_f32_16x16x32_bf16(af[1][m], bfr[1][n], acc[m][n], 0, 0, 0);
      }
    __builtin_amdgcn_s_setprio(0);
    __syncthreads();
  }

  // epilogue: C/D layout col=lane&15, row=(lane>>4)*4+j (m89-verified)
  #pragma unroll
  for (int n = 0; n < 4; ++n) {
    int ng = n0 + wc * 64 + n * 16 + cl;
    float bv = bias[ng];
    if constexpr (EPI == 0) {
      int part = ng >> 10;         // 0=Q 1=K 2=V
      int r = ng & 1023;
      int h = r >> 6, dk = r & 63;
      #pragma unroll
      for (int m = 0; m < 4; ++m)
        #pragma unroll
        for (int j = 0; j < 4; ++j) {
          int mg = m0 + wr * 64 + m * 16 + hl * 4 + j;
          int b = mg >> 11, s = mg & 2047;
          float val = acc[m][n][j] + bv;
          size_t bh = (size_t)(b * N_HEADS + h);
          if (part == 0)
            qout[(bh * S_LEN + s) * D_HEAD + dk] = f2bf(val * Q_SCALE);
          else if (part == 1)
            kout[(bh * S_LEN + s) * D_HEAD + dk] = f2bf(val);
          else
            vtout[(bh * D_HEAD + dk) * S_LEN + s] = f2bf(val);
        }
    } else {
      #pragma unroll
      for (int m = 0; m < 4; ++m)
        #pragma unroll
        for (int j = 0; j < 4; ++j) {
          int mg = m0 + wr * 64 + m * 16 + hl * 4 + j;
          fout[(size_t)mg * N + ng] = acc[m][n][j] + bv;
        }
    }
  }
}

// ---------------------------------------------------------------------------
// Flash attention, causal, exp2-domain softmax. Grid (B*H, S/128).
// Block = 8 waves (512 thr) covering 128 q-rows with a 2-way K-split:
//   waves 0-3: kt in [0, qt+1)           (row-groups wq=w&3)
//   waves 4-7: kt in [qt+1, 2qt+2)       (same rows, upper K half)
// Both halves do exactly qt+1 iterations (balanced). Partials merged via LDS.
// Each wave owns rows {qbase+wq*16, qbase+64+wq*16} (two 16-row fragments).
// launch_bounds(512,2): 2 blocks/CU -> 4 waves/EU -> 128 VGPR cap (no spill).
__global__ __launch_bounds__(512, 2) void attn_fwd(
    const bf16_t* __restrict__ q,    // [B,H,S,DK], pre-scaled by Q_SCALE
    const bf16_t* __restrict__ k,    // [B,H,S,DK]
    const bf16_t* __restrict__ vt,   // [B,H,DK,S]
    bf16_t* __restrict__ ao) {       // [B*S, H*DK]
  const int bh = blockIdx.x;
  const int qt = (S_LEN / 128 - 1) - blockIdx.y;   // long blocks first
  const int tid = threadIdx.x;
  const int lane = tid & 63, w = tid >> 6;
  const int wq = w & 3, half = w >> 2;
  const int cl = lane & 15, hl = lane >> 4;
  const bf16_t* qb = q + (size_t)bh * S_LEN * D_HEAD;
  const bf16_t* kb = k + (size_t)bh * S_LEN * D_HEAD;
  const bf16_t* vb = vt + (size_t)bh * D_HEAD * S_LEN;
  const int qbase = qt * 128;
  const int row0[2] = { qbase + wq * 16, qbase + 64 + wq * 16 };

  // smem: phase 1 = per-wave P tiles [8][32][72] bf16 (36864 B)
  //       phase 2 = merge buffer [4][64][48] f32 (49152 B)  (barrier-separated)
  __shared__ __align__(16) char smem[49152];
  auto plds = reinterpret_cast<bf16_t(*)[32][72]>(smem);
  float* mbuf = reinterpret_cast<float*>(smem);

  // Q fragments (A-operand): row=lane&15, k=(lane>>4)*8 (+32 for second half)
  bf16x8 qf[2][2];
  #pragma unroll
  for (int rf = 0; rf < 2; ++rf) {
    const bf16_t* qr = qb + (size_t)(row0[rf] + cl) * D_HEAD + hl * 8;
    qf[rf][0] = *reinterpret_cast<const bf16x8*>(qr);
    qf[rf][1] = *reinterpret_cast<const bf16x8*>(qr + 32);
  }

  float mrow[2][4], lrow[2][4];
  f32x4 acco[2][4];
  #pragma unroll
  for (int rf = 0; rf < 2; ++rf) {
    #pragma unroll
    for (int j = 0; j < 4; ++j) { mrow[rf][j] = -1e30f; lrow[rf][j] = 0.f; }
    #pragma unroll
    for (int db = 0; db < 4; ++db) acco[rf][db] = (f32x4){0.f, 0.f, 0.f, 0.f};
  }

  const int kt0 = half ? (qt + 1) : 0;
  const int kt1 = half ? (2 * qt + 2) : (qt + 1);
  for (int kt = kt0; kt < kt1; ++kt) {
    // K fragments, shared by both row-fragments
    bf16x8 kf[4][2];
    #pragma unroll
    for (int nb = 0; nb < 4; ++nb) {
      const bf16_t* kr = kb + (size_t)(kt * 64 + nb * 16 + cl) * D_HEAD + hl * 8;
      kf[nb][0] = *reinterpret_cast<const bf16x8*>(kr);
      kf[nb][1] = *reinterpret_cast<const bf16x8*>(kr + 32);
    }

    const bool act0 = (kt * 64) <= (row0[0] + 15);
    const bool act1 = (kt * 64) <= (row0[1] + 15);

    // QK^T for both fragments
    f32x4 sacc[2][4];
    __builtin_amdgcn_s_setprio(1);
    #pragma unroll
    for (int rf = 0; rf < 2; ++rf) {
      const bool act = rf ? act1 : act0;
      if (!act) continue;
      #pragma unroll
      for (int nb = 0; nb < 4; ++nb) {
        f32x4 s = (f32x4){0.f, 0.f, 0.f, 0.f};
        s = __builtin_amdgcn_mfma_f32_16x16x32_bf16(qf[rf][0], kf[nb][0], s, 0, 0, 0);
        s = __builtin_amdgcn_mfma_f32_16x16x32_bf16(qf[rf][1], kf[nb][1], s, 0, 0, 0);
        sacc[rf][nb] = s;
      }
    }
    __builtin_amdgcn_s_setprio(0);

    // V fragments issued early (in flight under softmax)
    bf16x8 vf[4][2];
    #pragma unroll
    for (int db = 0; db < 4; ++db) {
      const bf16_t* vr = vb + (size_t)(db * 16 + cl) * S_LEN + kt * 64 + hl * 8;
      vf[db][0] = *reinterpret_cast<const bf16x8*>(vr);
      vf[db][1] = *reinterpret_cast<const bf16x8*>(vr + 32);
    }

    // softmax (exp2 domain) + P->LDS
    #pragma unroll
    for (int rf = 0; rf < 2; ++rf) {
      const bool act = rf ? act1 : act0;
      if (!act) continue;
      if (kt * 64 + 63 > row0[rf]) {  // diagonal overlap: causal mask
        #pragma unroll
        for (int nb = 0; nb < 4; ++nb)
          #pragma unroll
          for (int j = 0; j < 4; ++j) {
            int colg = kt * 64 + nb * 16 + cl;
            int rowg = row0[rf] + hl * 4 + j;
            if (colg > rowg) sacc[rf][nb][j] = -1e30f;
          }
      }
      #pragma unroll
      for (int j = 0; j < 4; ++j) {
        float tmax = fmaxf(fmaxf(sacc[rf][0][j], sacc[rf][1][j]),
                           fmaxf(sacc[rf][2][j], sacc[rf][3][j]));
        tmax = fmaxf(tmax, __shfl_xor(tmax, 1));
        tmax = fmaxf(tmax, __shfl_xor(tmax, 2));
        tmax = fmaxf(tmax, __shfl_xor(tmax, 4));
        tmax = fmaxf(tmax, __shfl_xor(tmax, 8));
        float mnew = fmaxf(mrow[rf][j], tmax);
        float corr = __builtin_amdgcn_exp2f(mrow[rf][j] - mnew);
        mrow[rf][j] = mnew;
        float rsum = 0.f;
        #pragma unroll
        for (int nb = 0; nb < 4; ++nb) {
          float p = __builtin_amdgcn_exp2f(sacc[rf][nb][j] - mnew);
          sacc[rf][nb][j] = p;
          rsum += p;
        }
        rsum += __shfl_xor(rsum, 1);
        rsum += __shfl_xor(rsum, 2);
        rsum += __shfl_xor(rsum, 4);
        rsum += __shfl_xor(rsum, 8);
        lrow[rf][j] = lrow[rf][j] * corr + rsum;
        #pragma unroll
        for (int db = 0; db < 4; ++db) acco[rf][db][j] *= corr;
      }
      #pragma unroll
      for (int nb = 0; nb < 4; ++nb)
        #pragma unroll
        for (int j = 0; j < 4; ++j)
          plds[w][rf * 16 + hl * 4 + j][nb * 16 + cl] = f2bf(sacc[rf][nb][j]);
    }

    // PV
    __builtin_amdgcn_s_setprio(1);
    #pragma unroll
    for (int rf = 0; rf < 2; ++rf) {
      const bool act = rf ? act1 : act0;
      if (!act) continue;
      bf16x8 pf0 = *reinterpret_cast<const bf16x8*>(&plds[w][rf * 16 + cl][hl * 8]);
      bf16x8 pf1 = *reinterpret_cast<const bf16x8*>(&plds[w][rf * 16 + cl][32 + hl * 8]);
      #pragma unroll
      for (int db = 0; db < 4; ++db) {
        acco[rf][db] = __builtin_amdgcn_mfma_f32_16x16x32_bf16(pf0, vf[db][0], acco[rf][db], 0, 0, 0);
        acco[rf][db] = __builtin_amdgcn_mfma_f32_16x16x32_bf16(pf1, vf[db][1], acco[rf][db], 0, 0, 0);
      }
    }
    __builtin_amdgcn_s_setprio(0);
  }

  // merge the two K-halves (waves w and w+4 hold partials for the same rows)
  __syncthreads();
  if (half) {
    float* p = mbuf + ((size_t)((w - 4) * 64 + lane)) * 48;
    #pragma unroll
    for (int rf = 0; rf < 2; ++rf) {
      #pragma unroll
      for (int db = 0; db < 4; ++db)
        #pragma unroll
        for (int j = 0; j < 4; ++j)
          p[rf * 16 + db * 4 + j] = acco[rf][db][j];
      #pragma unroll
      for (int j = 0; j < 4; ++j) {
        p[32 + rf * 4 + j] = mrow[rf][j];
        p[40 + rf * 4 + j] = lrow[rf][j];
      }
    }
  }
  __syncthreads();
  if (!half) {
    const float* p = mbuf + ((size_t)(w * 64 + lane)) * 48;
    const int b = bh >> 4, h = bh & 15;
    #pragma unroll
    for (int rf = 0; rf < 2; ++rf) {
      float c1[4], c2[4], linv[4];
      #pragma unroll
      for (int j = 0; j < 4; ++j) {
        float m2 = p[32 + rf * 4 + j];
        float l2 = p[40 + rf * 4 + j];
        float m = fmaxf(mrow[rf][j], m2);
        c1[j] = __builtin_amdgcn_exp2f(mrow[rf][j] - m);
        c2[j] = __builtin_amdgcn_exp2f(m2 - m);
        linv[j] = 1.f / (lrow[rf][j] * c1[j] + l2 * c2[j]);
      }
      #pragma unroll
      for (int db = 0; db < 4; ++db)
        #pragma unroll
        for (int j = 0; j < 4; ++j) {
          int rowg = row0[rf] + hl * 4 + j;
          float o = (acco[rf][db][j] * c1[j] + p[rf * 16 + db * 4 + j] * c2[j]) * linv[j];
          ao[((size_t)(b * S_LEN) + rowg) * D_MODEL + h * D_HEAD + db * 16 + cl] = f2bf(o);
        }
    }
  }
}

// ---------------------------------------------------------------------------
extern "C" void kernel_launch(void* const* d_in, const int* in_sizes, int n_in,
                              void* d_out, int out_size, void* d_ws, size_t ws_size,
                              hipStream_t stream) {
  const float* x      = (const float*)d_in[0];
  const float* attn_w = (const float*)d_in[1];
  const float* attn_b = (const float*)d_in[2];
  const float* proj_w = (const float*)d_in[3];
  const float* proj_b = (const float*)d_in[4];
  float* out = (float*)d_out;
  char* ws = (char*)d_ws;

  bf16_t* xb  = (bf16_t*)(ws + OFF_XB);
  bf16_t* wb  = (bf16_t*)(ws + OFF_WB);
  bf16_t* pwb = (bf16_t*)(ws + OFF_PWB);
  bf16_t* qb  = (bf16_t*)(ws + OFF_Q);
  bf16_t* kb  = (bf16_t*)(ws + OFF_K);
  bf16_t* vtb = (bf16_t*)(ws + OFF_VT);
  bf16_t* aob = (bf16_t*)(ws + OFF_AO);

  const int n4a = M_ROWS * D_MODEL / 4;
  const int n4b = QKV_N * D_MODEL / 4;
  const int n4c = D_MODEL * D_MODEL / 4;
  const int n4 = n4a + n4b + n4c;
  cvt3_f32_bf16<<<(n4 + 255) / 256, 256, 0, stream>>>(x, xb, n4a, attn_w, wb, n4b,
                                                      proj_w, pwb, n4c);

  gemm_bt<0><<<dim3(QKV_N / BN, M_ROWS / BM), 256, 0, stream>>>(
      xb, wb, attn_b, nullptr, qb, kb, vtb, M_ROWS, QKV_N, D_MODEL);

  attn_fwd<<<dim3(B_SZ * N_HEADS, S_LEN / 128), 512, 0, stream>>>(qb, kb, vtb, aob);

  gemm_bt<1><<<dim3(D_MODEL / BN, M_ROWS / BM), 256, 0, stream>>>(
      aob, pwb, proj_b, out, nullptr, nullptr, nullptr, M_ROWS, D_MODEL, D_MODEL);
}

// Round 10
// 140.898 us; speedup vs baseline: 1.6972x; 1.0365x over previous
//
#include <hip/hip_runtime.h>
#include <hip/hip_bf16.h>
#include <stdint.h>

// ---------------------------------------------------------------------------
// OptimizedMultiHeadAttn: x:[2,2048,1024] f32, attn_w:[3072,1024], attn_b:[3072],
// proj_w:[1024,1024], proj_b:[1024]  ->  out:[2,2048,1024] f32
// Pipeline: cvt3 -> QKV gemm_bt (scatter Q/K/V^T) -> flash attn (swapped-QK,
// in-lane softmax, 8-wave K-split) -> proj gemm_bt
//
// R7 post-mortem: attn 77.6us, MfmaUtil 8.9%, VALUBusy 33% -> latency-bound on
// the 64 shfl_xor/iter softmax. This round: swapped-operand QK/PV so each lane
// owns a full q-row (softmax = in-lane tree + 2 shfl), cvt_pk packing,
// defer-max (THR=8), packed stores.
// (R8/R9: resubmissions — UnresponsiveContainer infra failures, no signal.)
// ---------------------------------------------------------------------------

typedef __bf16 bf16_t;
typedef __bf16 bf16x8 __attribute__((ext_vector_type(8)));
typedef float f32x4 __attribute__((ext_vector_type(4)));

#define B_SZ 2
#define S_LEN 2048
#define D_MODEL 1024
#define N_HEADS 16
#define D_HEAD 64
#define M_ROWS (B_SZ * S_LEN)          // 4096
#define QKV_N (3 * N_HEADS * D_HEAD)   // 3072

// Q pre-scale: 1/sqrt(64) * log2(e)  (softmax runs in exp2 domain)
#define Q_SCALE 0.1803368801111204f

// workspace layout (bytes); total 48 MiB
#define OFF_XB  (0ull)
#define OFF_WB  (8ull  << 20)
#define OFF_PWB (14ull << 20)
#define OFF_Q   (16ull << 20)
#define OFF_K   (24ull << 20)
#define OFF_VT  (32ull << 20)
#define OFF_AO  (40ull << 20)

__device__ __forceinline__ unsigned short f2bf_u(float f) {
  union { float f; unsigned u; } v; v.f = f;
  unsigned r = v.u + 0x7fffu + ((v.u >> 16) & 1u);  // RNE
  return (unsigned short)(r >> 16);
}
__device__ __forceinline__ bf16_t f2bf(float f) {
  unsigned short u = f2bf_u(f);
  return __builtin_bit_cast(bf16_t, u);
}
// v_cvt_pk_bf16_f32: D[15:0]=bf16(lo), D[31:16]=bf16(hi) (RNE). No builtin.
__device__ __forceinline__ unsigned cvt_pk_bf16(float lo, float hi) {
  unsigned r;
  asm volatile("v_cvt_pk_bf16_f32 %0, %1, %2" : "=v"(r) : "v"(lo), "v"(hi));
  return r;
}

// ---------------------------------------------------------------------------
__global__ void cvt3_f32_bf16(const float* __restrict__ sa, bf16_t* __restrict__ da, int n4a,
                              const float* __restrict__ sb, bf16_t* __restrict__ db, int n4b,
                              const float* __restrict__ sc, bf16_t* __restrict__ dc, int n4c) {
  int i = blockIdx.x * blockDim.x + threadIdx.x;
  const float* s; bf16_t* d; int j = i;
  if (i < n4a) { s = sa; d = da; }
  else if ((j = i - n4a) < n4b) { s = sb; d = db; }
  else if ((j = i - n4a - n4b) < n4c) { s = sc; d = dc; }
  else return;
  float4 f = reinterpret_cast<const float4*>(s)[j];
  ushort4 o;
  o.x = f2bf_u(f.x); o.y = f2bf_u(f.y); o.z = f2bf_u(f.z); o.w = f2bf_u(f.w);
  reinterpret_cast<ushort4*>(d)[j] = o;
}

// ---------------------------------------------------------------------------
// gemm_bt: C[M,N] = A[M,K] * Bt[N,K]^T + bias, 128x128 tile, BK=64, 4 waves.
#define BM 128
#define BN 128
#define BK 64

__device__ __forceinline__ void gload_lds16(const bf16_t* g, bf16_t* l) {
  __builtin_amdgcn_global_load_lds((__attribute__((address_space(1))) void*)g,
                                   (__attribute__((address_space(3))) void*)l,
                                   16, 0, 0);
}

__device__ __forceinline__ bf16x8 lds_frag(const bf16_t* lds, int row, int kchunk) {
  int pos = kchunk ^ (row & 7);
  return *reinterpret_cast<const bf16x8*>(lds + row * BK + pos * 8);
}

template <int EPI>
__global__ __launch_bounds__(256, 2) void gemm_bt(
    const bf16_t* __restrict__ A, const bf16_t* __restrict__ Bt,
    const float* __restrict__ bias,
    float* __restrict__ fout,
    bf16_t* __restrict__ qout, bf16_t* __restrict__ kout,
    bf16_t* __restrict__ vtout,
    int M, int N, int K) {
  __shared__ bf16_t As[BM * BK];
  __shared__ bf16_t Bs[BN * BK];
  const int tid = threadIdx.x;
  const int lane = tid & 63;
  const int wid = tid >> 6;
  const int wr = wid >> 1, wc = wid & 1;
  const int cl = lane & 15, hl = lane >> 4;
  const int m0 = blockIdx.y * BM, n0 = blockIdx.x * BN;

  f32x4 acc[4][4];
  #pragma unroll
  for (int m = 0; m < 4; ++m)
    #pragma unroll
    for (int n = 0; n < 4; ++n)
      acc[m][n] = (f32x4){0.f, 0.f, 0.f, 0.f};

  for (int kt = 0; kt < K; kt += BK) {
    #pragma unroll
    for (int it = 0; it < 4; ++it) {
      int chunk = it * 256 + tid;
      int row = chunk >> 3, cpos = chunk & 7;
      int csrc = cpos ^ (row & 7);
      bf16_t* ldsA = As + (it * 256 + wid * 64) * 8;
      bf16_t* ldsB = Bs + (it * 256 + wid * 64) * 8;
      gload_lds16(A  + (size_t)(m0 + row) * K + kt + csrc * 8, ldsA);
      gload_lds16(Bt + (size_t)(n0 + row) * K + kt + csrc * 8, ldsB);
    }
    __syncthreads();

    bf16x8 af[2][4], bfr[2][4];
    #pragma unroll
    for (int kk = 0; kk < 2; ++kk) {
      #pragma unroll
      for (int m = 0; m < 4; ++m)
        af[kk][m] = lds_frag(As, wr * 64 + m * 16 + cl, kk * 4 + hl);
      #pragma unroll
      for (int n = 0; n < 4; ++n)
        bfr[kk][n] = lds_frag(Bs, wc * 64 + n * 16 + cl, kk * 4 + hl);
    }
    __builtin_amdgcn_s_setprio(1);
    #pragma unroll
    for (int m = 0; m < 4; ++m)
      #pragma unroll
      for (int n = 0; n < 4; ++n) {
        acc[m][n] = __builtin_amdgcn_mfma_f32_16x16x32_bf16(af[0][m], bfr[0][n], acc[m][n], 0, 0, 0);
        acc[m][n] = __builtin_amdgcn_mfma_f32_16x16x32_bf16(af[1][m], bfr[1][n], acc[m][n], 0, 0, 0);
      }
    __builtin_amdgcn_s_setprio(0);
    __syncthreads();
  }

  #pragma unroll
  for (int n = 0; n < 4; ++n) {
    int ng = n0 + wc * 64 + n * 16 + cl;
    float bv = bias[ng];
    if constexpr (EPI == 0) {
      int part = ng >> 10;         // 0=Q 1=K 2=V
      int r = ng & 1023;
      int h = r >> 6, dk = r & 63;
      #pragma unroll
      for (int m = 0; m < 4; ++m)
        #pragma unroll
        for (int j = 0; j < 4; ++j) {
          int mg = m0 + wr * 64 + m * 16 + hl * 4 + j;
          int b = mg >> 11, s = mg & 2047;
          float val = acc[m][n][j] + bv;
          size_t bh = (size_t)(b * N_HEADS + h);
          if (part == 0)
            qout[(bh * S_LEN + s) * D_HEAD + dk] = f2bf(val * Q_SCALE);
          else if (part == 1)
            kout[(bh * S_LEN + s) * D_HEAD + dk] = f2bf(val);
          else
            vtout[(bh * D_HEAD + dk) * S_LEN + s] = f2bf(val);
        }
    } else {
      #pragma unroll
      for (int m = 0; m < 4; ++m)
        #pragma unroll
        for (int j = 0; j < 4; ++j) {
          int mg = m0 + wr * 64 + m * 16 + hl * 4 + j;
          fout[(size_t)mg * N + ng] = acc[m][n][j] + bv;
        }
    }
  }
}

// ---------------------------------------------------------------------------
// Flash attention, causal, exp2 domain, SWAPPED-OPERAND layout:
//   QK:  s = mfma(K, Q)  -> lane (cl,hl) holds S[qrow=row0+cl][kpos=nb*16+hl*4+jj]
//        (16 scores of ONE q-row per lane -> in-lane max/sum + 2 shfl_xor)
//   PV:  acco = mfma(V^T, P) -> acco[d=db*16+hl*4+j][qrow=cl]; softmax state
//        (m,l scalars, qrow=cl) aligns with acco for in-register rescale.
// 8 waves, 2-way K-split (waves 0-3 lower half, 4-7 upper), merge via LDS.
__global__ __launch_bounds__(512, 2) void attn_fwd(
    const bf16_t* __restrict__ q,    // [B,H,S,DK], pre-scaled by Q_SCALE
    const bf16_t* __restrict__ k,    // [B,H,S,DK]
    const bf16_t* __restrict__ vt,   // [B,H,DK,S]
    bf16_t* __restrict__ ao) {       // [B*S, H*DK]
  const int bh = blockIdx.x;
  const int qt = (S_LEN / 128 - 1) - blockIdx.y;   // long blocks first
  const int tid = threadIdx.x;
  const int lane = tid & 63, w = tid >> 6;
  const int wq = w & 3, half = w >> 2;
  const int cl = lane & 15, hl = lane >> 4;
  const bf16_t* qb = q + (size_t)bh * S_LEN * D_HEAD;
  const bf16_t* kb = k + (size_t)bh * S_LEN * D_HEAD;
  const bf16_t* vb = vt + (size_t)bh * D_HEAD * S_LEN;
  const int qbase = qt * 128;
  const int row0[2] = { qbase + wq * 16, qbase + 64 + wq * 16 };

  // phase 1: per-wave P tiles [8][32 rows=rf*16+qrow][72 kpos-padded] bf16 (36864 B)
  // phase 2: merge buffer [4][64][36] f32 (36864 B), barrier-separated
  __shared__ __align__(16) char smem[36864];
  auto plds = reinterpret_cast<bf16_t(*)[32][72]>(smem);
  float* mbuf = reinterpret_cast<float*>(smem);

  // Q fragments: lane (cl,hl) holds Q[row0+cl][hl*8+e] -> B-operand (j=qrow, kk=d)
  bf16x8 qf[2][2];
  #pragma unroll
  for (int rf = 0; rf < 2; ++rf) {
    const bf16_t* qr = qb + (size_t)(row0[rf] + cl) * D_HEAD + hl * 8;
    qf[rf][0] = *reinterpret_cast<const bf16x8*>(qr);
    qf[rf][1] = *reinterpret_cast<const bf16x8*>(qr + 32);
  }

  float mrow[2], lrow[2];
  f32x4 acco[2][4];
  #pragma unroll
  for (int rf = 0; rf < 2; ++rf) {
    mrow[rf] = -1e30f; lrow[rf] = 0.f;
    #pragma unroll
    for (int db = 0; db < 4; ++db) acco[rf][db] = (f32x4){0.f, 0.f, 0.f, 0.f};
  }

  const int kt0 = half ? (qt + 1) : 0;
  const int kt1 = half ? (2 * qt + 2) : (qt + 1);
  for (int kt = kt0; kt < kt1; ++kt) {
    // K fragments: lane (cl,hl) holds K[kt*64+nb*16+cl][hl*8+e] -> A-operand
    bf16x8 kf[4][2];
    #pragma unroll
    for (int nb = 0; nb < 4; ++nb) {
      const bf16_t* kr = kb + (size_t)(kt * 64 + nb * 16 + cl) * D_HEAD + hl * 8;
      kf[nb][0] = *reinterpret_cast<const bf16x8*>(kr);
      kf[nb][1] = *reinterpret_cast<const bf16x8*>(kr + 32);
    }

    const bool act0 = (kt * 64) <= (row0[0] + 15);
    const bool act1 = (kt * 64) <= (row0[1] + 15);

    // QK^T swapped: sacc[rf][nb][jj] = S[qrow=row0+cl][kpos=kt*64+nb*16+hl*4+jj]
    f32x4 sacc[2][4];
    __builtin_amdgcn_s_setprio(1);
    #pragma unroll
    for (int rf = 0; rf < 2; ++rf) {
      const bool act = rf ? act1 : act0;
      if (!act) continue;
      #pragma unroll
      for (int nb = 0; nb < 4; ++nb) {
        f32x4 s = (f32x4){0.f, 0.f, 0.f, 0.f};
        s = __builtin_amdgcn_mfma_f32_16x16x32_bf16(kf[nb][0], qf[rf][0], s, 0, 0, 0);
        s = __builtin_amdgcn_mfma_f32_16x16x32_bf16(kf[nb][1], qf[rf][1], s, 0, 0, 0);
        sacc[rf][nb] = s;
      }
    }
    __builtin_amdgcn_s_setprio(0);

    // V fragments (A-operand of PV): V^T[db*16+cl][kt*64+hl*8+e]
    bf16x8 vf[4][2];
    #pragma unroll
    for (int db = 0; db < 4; ++db) {
      const bf16_t* vr = vb + (size_t)(db * 16 + cl) * S_LEN + kt * 64 + hl * 8;
      vf[db][0] = *reinterpret_cast<const bf16x8*>(vr);
      vf[db][1] = *reinterpret_cast<const bf16x8*>(vr + 32);
    }

    // softmax: per-lane row state, in-lane reductions + 2 shfl
    #pragma unroll
    for (int rf = 0; rf < 2; ++rf) {
      const bool act = rf ? act1 : act0;
      if (!act) continue;
      const int qrow = row0[rf] + cl;
      if (kt * 64 + 63 > qrow) {  // diagonal overlap: causal mask
        #pragma unroll
        for (int nb = 0; nb < 4; ++nb)
          #pragma unroll
          for (int jj = 0; jj < 4; ++jj) {
            int kpos = kt * 64 + nb * 16 + hl * 4 + jj;
            if (kpos > qrow) sacc[rf][nb][jj] = -1e30f;
          }
      }
      float tm = sacc[rf][0][0];
      #pragma unroll
      for (int nb = 0; nb < 4; ++nb)
        #pragma unroll
        for (int jj = 0; jj < 4; ++jj)
          tm = fmaxf(tm, sacc[rf][nb][jj]);
      tm = fmaxf(tm, __shfl_xor(tm, 16));
      tm = fmaxf(tm, __shfl_xor(tm, 32));
      // defer-max (T13, THR=8): skip rescale while max growth is small
      if (__any(tm > mrow[rf] + 8.f)) {
        float mnew = fmaxf(mrow[rf], tm);
        float corr = __builtin_amdgcn_exp2f(mrow[rf] - mnew);
        mrow[rf] = mnew;
        lrow[rf] *= corr;
        #pragma unroll
        for (int db = 0; db < 4; ++db) acco[rf][db] *= corr;
      }
      float rs = 0.f;
      #pragma unroll
      for (int nb = 0; nb < 4; ++nb)
        #pragma unroll
        for (int jj = 0; jj < 4; ++jj) {
          float p = __builtin_amdgcn_exp2f(sacc[rf][nb][jj] - mrow[rf]);
          sacc[rf][nb][jj] = p;
          rs += p;
        }
      rs += __shfl_xor(rs, 16);
      rs += __shfl_xor(rs, 32);
      lrow[rf] += rs;
      // P -> LDS: row=rf*16+cl (qrow), col=kpos; cvt_pk pairs -> one b64/ nb
      #pragma unroll
      for (int nb = 0; nb < 4; ++nb) {
        uint2 u;
        u.x = cvt_pk_bf16(sacc[rf][nb][0], sacc[rf][nb][1]);
        u.y = cvt_pk_bf16(sacc[rf][nb][2], sacc[rf][nb][3]);
        *reinterpret_cast<uint2*>(&plds[w][rf * 16 + cl][nb * 16 + hl * 4]) = u;
      }
    }

    // PV swapped: acco = mfma(V^T, P): D[d=db*16+hl*4+j][qrow=cl]
    __builtin_amdgcn_s_setprio(1);
    #pragma unroll
    for (int rf = 0; rf < 2; ++rf) {
      const bool act = rf ? act1 : act0;
      if (!act) continue;
      bf16x8 pf0 = *reinterpret_cast<const bf16x8*>(&plds[w][rf * 16 + cl][hl * 8]);
      bf16x8 pf1 = *reinterpret_cast<const bf16x8*>(&plds[w][rf * 16 + cl][32 + hl * 8]);
      #pragma unroll
      for (int db = 0; db < 4; ++db) {
        acco[rf][db] = __builtin_amdgcn_mfma_f32_16x16x32_bf16(vf[db][0], pf0, acco[rf][db], 0, 0, 0);
        acco[rf][db] = __builtin_amdgcn_mfma_f32_16x16x32_bf16(vf[db][1], pf1, acco[rf][db], 0, 0, 0);
      }
    }
    __builtin_amdgcn_s_setprio(0);
  }

  // merge the two K-halves (waves w and w+4 hold partials for the same rows)
  __syncthreads();
  if (half) {
    float* p = mbuf + (size_t)((w - 4) * 64 + lane) * 36;
    #pragma unroll
    for (int rf = 0; rf < 2; ++rf)
      #pragma unroll
      for (int db = 0; db < 4; ++db)
        #pragma unroll
        for (int j = 0; j < 4; ++j)
          p[rf * 16 + db * 4 + j] = acco[rf][db][j];
    p[32] = mrow[0]; p[33] = mrow[1];
    p[34] = lrow[0]; p[35] = lrow[1];
  }
  __syncthreads();
  if (!half) {
    const float* p = mbuf + (size_t)(w * 64 + lane) * 36;
    const int b = bh >> 4, h = bh & 15;
    #pragma unroll
    for (int rf = 0; rf < 2; ++rf) {
      float m2 = p[32 + rf], l2 = p[34 + rf];
      float m = fmaxf(mrow[rf], m2);
      float c1 = __builtin_amdgcn_exp2f(mrow[rf] - m);
      float c2 = __builtin_amdgcn_exp2f(m2 - m);
      float linv = 1.f / (lrow[rf] * c1 + l2 * c2);
      const int qrow = row0[rf] + cl;
      #pragma unroll
      for (int db = 0; db < 4; ++db) {
        float o[4];
        #pragma unroll
        for (int j = 0; j < 4; ++j)
          o[j] = (acco[rf][db][j] * c1 + p[rf * 16 + db * 4 + j] * c2) * linv;
        uint2 u;
        u.x = cvt_pk_bf16(o[0], o[1]);
        u.y = cvt_pk_bf16(o[2], o[3]);
        *reinterpret_cast<uint2*>(
            ao + ((size_t)(b * S_LEN) + qrow) * D_MODEL + h * D_HEAD + db * 16 + hl * 4) = u;
      }
    }
  }
}

// ---------------------------------------------------------------------------
extern "C" void kernel_launch(void* const* d_in, const int* in_sizes, int n_in,
                              void* d_out, int out_size, void* d_ws, size_t ws_size,
                              hipStream_t stream) {
  const float* x      = (const float*)d_in[0];
  const float* attn_w = (const float*)d_in[1];
  const float* attn_b = (const float*)d_in[2];
  const float* proj_w = (const float*)d_in[3];
  const float* proj_b = (const float*)d_in[4];
  float* out = (float*)d_out;
  char* ws = (char*)d_ws;

  bf16_t* xb  = (bf16_t*)(ws + OFF_XB);
  bf16_t* wb  = (bf16_t*)(ws + OFF_WB);
  bf16_t* pwb = (bf16_t*)(ws + OFF_PWB);
  bf16_t* qb  = (bf16_t*)(ws + OFF_Q);
  bf16_t* kb  = (bf16_t*)(ws + OFF_K);
  bf16_t* vtb = (bf16_t*)(ws + OFF_VT);
  bf16_t* aob = (bf16_t*)(ws + OFF_AO);

  const int n4a = M_ROWS * D_MODEL / 4;
  const int n4b = QKV_N * D_MODEL / 4;
  const int n4c = D_MODEL * D_MODEL / 4;
  const int n4 = n4a + n4b + n4c;
  cvt3_f32_bf16<<<(n4 + 255) / 256, 256, 0, stream>>>(x, xb, n4a, attn_w, wb, n4b,
                                                      proj_w, pwb, n4c);

  gemm_bt<0><<<dim3(QKV_N / BN, M_ROWS / BM), 256, 0, stream>>>(
      xb, wb, attn_b, nullptr, qb, kb, vtb, M_ROWS, QKV_N, D_MODEL);

  attn_fwd<<<dim3(B_SZ * N_HEADS, S_LEN / 128), 512, 0, stream>>>(qb, kb, vtb, aob);

  gemm_bt<1><<<dim3(D_MODEL / BN, M_ROWS / BM), 256, 0, stream>>>(
      aob, pwb, proj_b, out, nullptr, nullptr, nullptr, M_ROWS, D_MODEL, D_MODEL);
}